// Round 7
// baseline (135.796 us; speedup 1.0000x reference)
//
#include <hip/hip_runtime.h>
#include <hip/hip_bf16.h>

// BatchedNLM: per-neuron 2-layer GLU MLP.
//   state_trace (128,2048,32) f32, fc1_w (2048,32,256), fc1_b (2048,256),
//   fc2_w (2048,128,2), fc2_b (2048,2), T (1)  ->  out (128,2048) f32
//
// One block per 4 neurons (pipelined). 256 threads = 4 waves; wave w owns
// batches [32w,32w+32). GEMM1 via mfma_f32_16x16x32_bf16 (K=32, one MFMA).
// GLU1 pairs (h, h+128) = tiles (p, p+8): same lane/reg -> register-only.
// fc2 (K=128, N=2) folded into tile loop as per-lane partials + shfl_xor tree.
//
// R5 WIN (94->46): w1 via global_load_lds width=16 (async DMA, no VGPRs).
// R6 WIN (46->40): rcpf sigmoid + LDS alias. Profile: FETCH 51 MB at 1.3 TB/s
//     = kernel duration -> fetch is latency/burst-limited, not BW-limited.
//     All resident blocks fetch->barrier->compute in lockstep; no overlap.
// R7: neuron pipeline. NPB=4 neurons/block, grid 512. Separate ldsW (raw f32)
//     and ldsB (bf16 frag) so conversion has NO internal barrier; DMA(i+1) and
//     A-loads(i+1) issue right after the barrier that frees ldsW, landing
//     during compute(i) (next drain is one full compute phase later).
//     2 barriers/neuron (was 4). out_t rows batched: one 2 KB store per block.
//     ~88 us of the timed figure is harness overhead (d_ws poison fills at
//     40 us x2 + restores) — actionable budget is nlm + transpose only.

#define NN 2048
#define NPB 4

typedef __attribute__((ext_vector_type(8))) short short8;
typedef __attribute__((ext_vector_type(4))) float floatx4;
typedef __attribute__((ext_vector_type(4))) int int4v;

static __device__ __forceinline__ unsigned int pkbf(float a, float b) {
    __hip_bfloat162 h = __float22bfloat162_rn(make_float2(a, b));  // v_cvt_pk_bf16_f32
    return *(unsigned int*)&h;
}

static __device__ __forceinline__ float sigmoidf(float x) {
    return __builtin_amdgcn_rcpf(1.0f + __expf(-x));   // no IEEE div sequence
}

static __device__ __forceinline__ void gload_lds16(const float* g, float* l) {
    // Per-lane gptr; LDS dest = wave-uniform base + lane*16B (m97/m104 semantics).
    __builtin_amdgcn_global_load_lds((const __attribute__((address_space(1))) void*)g,
                                     (__attribute__((address_space(3))) void*)l,
                                     16, 0, 0);
}

__global__ __launch_bounds__(256, 2)
void nlm_kernel(const float* __restrict__ st,
                const float* __restrict__ w1,
                const float* __restrict__ b1,
                const float* __restrict__ w2,
                const float* __restrict__ b2,
                const float* __restrict__ Tp,
                float* __restrict__ out_t)
{
    const int n0 = blockIdx.x * NPB;
    const int t  = threadIdx.x;

    __shared__ __align__(16) float ldsW[32 * 256];      // raw f32 W1, 32 KB
    __shared__ __align__(16) short ldsB[16 * 64 * 8];   // bf16 frag-major, 16 KB
    __shared__ float4 ldsP[2][128];                     // param table, ping-pong
    __shared__ float  ldsO[NPB][128];                   // output rows

    const int lane = t & 63;
    const int wv   = t >> 6;      // wave 0..3
    const int m    = lane & 15;   // A row / C col
    const int quad = lane >> 4;   // k-quad / C row group

    const float* gW0 = w1 + (size_t)n0 * 8192;

    // A-frag staging registers, ping-pong across pipeline stages.
    floatx4 av[2][2][2];          // [stage&1][bt][half]
    float  pa_n = 0.f, pb_n = 0.f;
    float2 pw_n = make_float2(0.f, 0.f);

    // ---- Prologue: issue DMA(0), A(0), params(0) ----
    #pragma unroll
    for (int j = 0; j < 8; ++j) {
        const int off = wv * 2048 + j * 256;
        gload_lds16(gW0 + off + lane * 4, &ldsW[off]);
    }
    #pragma unroll
    for (int bt = 0; bt < 2; ++bt) {
        const int b = wv * 32 + bt * 16 + m;
        const float* sp = st + (size_t)b * (NN * 32) + (size_t)n0 * 32 + quad * 8;
        av[0][bt][0] = *(const floatx4*)sp;
        av[0][bt][1] = *(const floatx4*)(sp + 4);
    }
    if (t < 128) {
        const float* b1p = b1 + n0 * 256;
        const float* w2p = w2 + n0 * 256;
        float  pa = b1p[t];
        float  pb = b1p[128 + t];
        float2 pw = *(const float2*)(w2p + 2 * t);
        ldsP[0][t] = make_float4(pa, pb, pw.x, pw.y);
    }

    const float invT = 1.0f / Tp[0];

    #pragma unroll
    for (int i = 0; i < NPB; ++i) {
        __syncthreads();   // barrier1: DMA(i) drained; ldsP[i&1] visible

        // ---- Convert ldsW (f32) -> ldsB (bf16 frag-major). No barrier inside:
        // reads and writes hit different buffers. Reads 2-way bank alias = free.
        {
            const int base = ((t >> 4) * 512) + ((t & 15) * 8); // shorts
            #pragma unroll
            for (int q = 0; q < 4; ++q) {
                float w8[8];
                #pragma unroll
                for (int j = 0; j < 8; ++j)
                    w8[j] = ldsW[(q * 8 + j) * 256 + t];
                union { int4v iv; short8 s; } u;
                #pragma unroll
                for (int e = 0; e < 4; ++e)
                    u.iv[e] = pkbf(w8[2 * e], w8[2 * e + 1]);
                *(short8*)&ldsB[base + q * 128] = u.s;
            }
        }

        __syncthreads();   // barrier2: ldsB ready; ldsW free for DMA(i+1)

        // ---- Prefetch stage i+1 (lands during compute(i); next drain is
        // barrier1 of iter i+1, one full compute phase away) ----
        if (i + 1 < NPB) {
            const float* gW = w1 + (size_t)(n0 + i + 1) * 8192;
            #pragma unroll
            for (int j = 0; j < 8; ++j) {
                const int off = wv * 2048 + j * 256;
                gload_lds16(gW + off + lane * 4, &ldsW[off]);
            }
            #pragma unroll
            for (int bt = 0; bt < 2; ++bt) {
                const int b = wv * 32 + bt * 16 + m;
                const float* sp = st + (size_t)b * (NN * 32)
                                     + (size_t)(n0 + i + 1) * 32 + quad * 8;
                av[(i + 1) & 1][bt][0] = *(const floatx4*)sp;
                av[(i + 1) & 1][bt][1] = *(const floatx4*)(sp + 4);
            }
            if (t < 128) {
                const float* b1p = b1 + (n0 + i + 1) * 256;
                const float* w2p = w2 + (n0 + i + 1) * 256;
                pa_n = b1p[t];
                pb_n = b1p[128 + t];
                pw_n = *(const float2*)(w2p + 2 * t);
            }
        }

        // ---- A fragments for neuron i ----
        short8 afrag[2];
        #pragma unroll
        for (int bt = 0; bt < 2; ++bt) {
            union { int4v iv; short8 s; } u;
            u.iv[0] = pkbf(av[i & 1][bt][0][0], av[i & 1][bt][0][1]);
            u.iv[1] = pkbf(av[i & 1][bt][0][2], av[i & 1][bt][0][3]);
            u.iv[2] = pkbf(av[i & 1][bt][1][0], av[i & 1][bt][1][1]);
            u.iv[3] = pkbf(av[i & 1][bt][1][2], av[i & 1][bt][1][3]);
            afrag[bt] = u.s;
        }

        // ---- Compute: 8 tile-pairs, fc2 folded in ----
        float pacc[2][4][2];
        #pragma unroll
        for (int bt = 0; bt < 2; ++bt)
            #pragma unroll
            for (int r = 0; r < 4; ++r)
                pacc[bt][r][0] = pacc[bt][r][1] = 0.0f;

        #pragma unroll
        for (int p = 0; p < 8; ++p) {
            short8 bfA = *(short8*)&ldsB[(p * 64 + lane) * 8];
            short8 bfB = *(short8*)&ldsB[((p + 8) * 64 + lane) * 8];
            float4 prm = ldsP[i & 1][p * 16 + m];

            #pragma unroll
            for (int bt = 0; bt < 2; ++bt) {
                floatx4 z = {0.0f, 0.0f, 0.0f, 0.0f};
                floatx4 xa = __builtin_amdgcn_mfma_f32_16x16x32_bf16(afrag[bt], bfA, z, 0, 0, 0);
                floatx4 xb = __builtin_amdgcn_mfma_f32_16x16x32_bf16(afrag[bt], bfB, z, 0, 0, 0);
                #pragma unroll
                for (int r = 0; r < 4; ++r) {
                    float a   = xa[r] + prm.x;
                    float g   = xb[r] + prm.y;
                    float glu = a * sigmoidf(g);
                    pacc[bt][r][0] += glu * prm.z;
                    pacc[bt][r][1] += glu * prm.w;
                }
            }
        }

        // ---- Reduce fc2 partials across the 16 lanes of each quad ----
        const float bb0 = b2[(n0 + i) * 2 + 0];
        const float bb1 = b2[(n0 + i) * 2 + 1];

        #pragma unroll
        for (int bt = 0; bt < 2; ++bt) {
            #pragma unroll
            for (int r = 0; r < 4; ++r) {
                float s0 = pacc[bt][r][0];
                float s1 = pacc[bt][r][1];
                s0 += __shfl_xor(s0, 1);  s1 += __shfl_xor(s1, 1);
                s0 += __shfl_xor(s0, 2);  s1 += __shfl_xor(s1, 2);
                s0 += __shfl_xor(s0, 4);  s1 += __shfl_xor(s1, 4);
                s0 += __shfl_xor(s0, 8);  s1 += __shfl_xor(s1, 8);
                if (m == 0) {
                    const int b = wv * 32 + bt * 16 + quad * 4 + r;
                    float x0 = s0 + bb0;
                    float x1 = s1 + bb1;
                    ldsO[i][b] = x0 * sigmoidf(x1) * invT;
                }
            }
        }

        // Stage params for neuron i+1 into the other ldsP bank (not read by
        // compute(i)); visible to all after barrier1 of iter i+1.
        if (i + 1 < NPB && t < 128)
            ldsP[(i + 1) & 1][t] = make_float4(pa_n, pb_n, pw_n.x, pw_n.y);
    }

    __syncthreads();

    // One coalesced 2 KB store: 4 consecutive out_t rows (512 floats).
    {
        float2* dst = (float2*)(out_t + (size_t)n0 * 128);
        dst[t] = ((const float2*)ldsO)[t];
    }
}

// Transpose out_t (2048,128) -> out (128,2048). 32x32 tiles, 256 blocks.
__global__ __launch_bounds__(256)
void transpose_kernel(const float* __restrict__ out_t, float* __restrict__ out)
{
    __shared__ float tile[32][33];
    const int t    = threadIdx.x;
    const int bidx = blockIdx.x;           // 0..255
    const int n0   = (bidx & 63) * 32;     // 64 n-tiles
    const int b0   = (bidx >> 6) * 32;     // 4 b-tiles

    const int tx = t & 31;
    const int ty = t >> 5;                 // 0..7

    #pragma unroll
    for (int i = 0; i < 4; ++i) {
        const int nl = ty + i * 8;
        tile[nl][tx] = out_t[(size_t)(n0 + nl) * 128 + b0 + tx];
    }

    __syncthreads();

    #pragma unroll
    for (int i = 0; i < 4; ++i) {
        const int bl = ty + i * 8;
        out[(size_t)(b0 + bl) * NN + n0 + tx] = tile[tx][bl];
    }
}

extern "C" void kernel_launch(void* const* d_in, const int* in_sizes, int n_in,
                              void* d_out, int out_size, void* d_ws, size_t ws_size,
                              hipStream_t stream) {
    const float* st = (const float*)d_in[0];
    const float* w1 = (const float*)d_in[1];
    const float* b1 = (const float*)d_in[2];
    const float* w2 = (const float*)d_in[3];
    const float* b2 = (const float*)d_in[4];
    const float* T  = (const float*)d_in[5];
    float* out   = (float*)d_out;
    float* out_t = (float*)d_ws;    // 2048*128*4 = 1 MB scratch

    nlm_kernel<<<dim3(NN / NPB), dim3(256), 0, stream>>>(st, w1, b1, w2, b2, T, out_t);
    transpose_kernel<<<dim3(256), dim3(256), 0, stream>>>(out_t, out);
}